// Round 13
// baseline (152.102 us; speedup 1.0000x reference)
//
#include <hip/hip_runtime.h>
#include <hip/hip_bf16.h>

typedef __bf16 bf16;
typedef __bf16 bf16x4 __attribute__((ext_vector_type(4)));
typedef __bf16 bf16x8 __attribute__((ext_vector_type(8)));
typedef float f32x4 __attribute__((ext_vector_type(4)));

#define MFMA_16x16x32(A, B, C) __builtin_amdgcn_mfma_f32_16x16x32_bf16(A, B, C, 0, 0, 0)

static_assert(sizeof(bf16x8) == 16, "bf16x8 must be 16B");

// ---------------------------------------------------------------------------
// Kernel 0: cast + transpose weights: Wt[p][h][c] = W_p[c][h].
// ---------------------------------------------------------------------------
__global__ __launch_bounds__(256) void wtrans_kernel(
    const float* __restrict__ Wq, const float* __restrict__ Wk,
    const float* __restrict__ Wv, bf16* __restrict__ Wt)
{
  int idx = blockIdx.x * 256 + threadIdx.x;   // 3*64*1024
  int p = idx >> 16;
  int rem = idx & 65535;
  int h = rem >> 10;
  int c = rem & 1023;
  const float* W = (p == 0) ? Wq : (p == 1) ? Wk : Wv;
  Wt[idx] = (bf16)W[c * 64 + h];
}

// ---------------------------------------------------------------------------
// Kernel 1: projections — ADDRESS-SEQUENTIAL A reads (the untested axis).
// All 12 prior rounds read A "16 rows in parallel, k inner": each wave
// instruction gathers 16 strided pieces across 16 x 4KB rows -> DRAM
// page/channel thrash; effective HBM rate pinned ~1.2 TB/s regardless of
// structure. m13's 6.3 TB/s pattern = contiguous 1KB per instruction.
// Here: per k-quarter (256 f32), a wave issues 16 loads, EACH a fully
// contiguous 1KB (one row-quarter = one DRAM page), pages in order, all 16
// in flight at once (float4 L[16], full unroll -> 16KB/wave MLP).
// Redistribution to MFMA fragment layout via per-wave private LDS strip
// [16][280] — same-wave DS is in-order, so NO barrier (R12-verified).
// B staged per quarter ([64][280] tiles, pad kills conflicts).
// 512 blocks x 512 thr: bid<256 Q-family, else fused K+V (k read once).
// 1 block/CU (~140KB LDS), 8 waves; __launch_bounds__(512,2) -> 256 VGPR
// budget so L[16] survives regalloc.
// ---------------------------------------------------------------------------
__global__ __launch_bounds__(512, 2) void proj_kernel(
    const float* __restrict__ qin, const float* __restrict__ kin,
    const bf16* __restrict__ Wt,
    bf16* __restrict__ Qb, bf16* __restrict__ Kb, bf16* __restrict__ Vtb)
{
  extern __shared__ __align__(16) bf16 lds[];
  // B0 tile [64][280] @0 ; B1 tile [64][280] @17920 ; per-wave A stage
  // [16][280] @35840 + w*4480   (elements)
  const int tid = threadIdx.x;
  const int lane = tid & 63;
  const int w = tid >> 6;          // wave 0..7
  const int g = lane >> 4;
  const int r = lane & 15;

  const int bid = blockIdx.x;      // 0..511
  const bool isQ = (bid < 256);
  const int strip = (isQ ? bid : bid - 256) * 8 + w;   // 0..2047
  const float* A = isQ ? qin : kin;
  const float* ap = A + (size_t)strip * 16 * 1024 + lane * 4;

  bf16* const B0 = lds;
  bf16* const B1 = lds + 17920;
  bf16* const sA = lds + 35840 + w * 4480;

  f32x4 acc0[4], acc1[4];
  #pragma unroll
  for (int cf = 0; cf < 4; cf++) {
    acc0[cf] = (f32x4){0.f, 0.f, 0.f, 0.f};
    acc1[cf] = (f32x4){0.f, 0.f, 0.f, 0.f};
  }

  for (int q = 0; q < 4; ++q) {
    if (q) __syncthreads();        // WAR: all waves done reading B[q-1]

    // --- stage B tiles for this quarter: [64][256] bf16 each ---
    #pragma unroll
    for (int i = 0; i < 4; ++i) {
      int c = i * 512 + tid;       // chunk 0..2047 (16B each)
      int row = c >> 5, ch = c & 31;
      bf16x8 v0 = *(const bf16x8*)(Wt + (size_t)(isQ ? 0 : 65536)
                                   + (size_t)row * 1024 + q * 256 + ch * 8);
      *(bf16x8*)&B0[row * 280 + ch * 8] = v0;
      if (!isQ) {
        bf16x8 v1 = *(const bf16x8*)(Wt + (size_t)2 * 65536
                                     + (size_t)row * 1024 + q * 256 + ch * 8);
        *(bf16x8*)&B1[row * 280 + ch * 8] = v1;
      }
    }
    __syncthreads();               // B visible

    // --- A: 16 address-sequential 1KB loads, all in flight ---
    float4 L[16];
    #pragma unroll
    for (int i = 0; i < 16; ++i)
      L[i] = *(const float4*)(ap + (size_t)i * 1024 + q * 256);

    // convert + write to per-wave stage (same-wave DS order: no barrier)
    #pragma unroll
    for (int i = 0; i < 16; ++i) {
      bf16x4 v = (bf16x4){(bf16)L[i].x, (bf16)L[i].y,
                          (bf16)L[i].z, (bf16)L[i].w};
      *(bf16x4*)&sA[i * 280 + lane * 4] = v;
    }

    // --- compute: 8 chunks of K=32 ---
    #pragma unroll
    for (int cl = 0; cl < 8; ++cl) {
      bf16x8 af = *(const bf16x8*)&sA[r * 280 + cl * 32 + g * 8];
      #pragma unroll
      for (int cf = 0; cf < 4; cf++) {
        bf16x8 b0 = *(const bf16x8*)&B0[(cf * 16 + r) * 280 + cl * 32 + g * 8];
        acc0[cf] = MFMA_16x16x32(af, b0, acc0[cf]);
        if (!isQ) {
          bf16x8 b1 = *(const bf16x8*)&B1[(cf * 16 + r) * 280 + cl * 32 + g * 8];
          acc1[cf] = MFMA_16x16x32(af, b1, acc1[cf]);
        }
      }
    }
  }

  // --- epilogue: C/D layout row=(l>>4)*4+j, col=l&15 ---
  if (isQ) {
    #pragma unroll
    for (int cf = 0; cf < 4; cf++)
      #pragma unroll
      for (int jj = 0; jj < 4; jj++) {
        int rg = strip * 16 + g * 4 + jj;
        Qb[(size_t)rg * 64 + cf * 16 + r] = (bf16)acc0[cf][jj];
      }
  } else {
    #pragma unroll
    for (int cf = 0; cf < 4; cf++)
      #pragma unroll
      for (int jj = 0; jj < 4; jj++) {
        int rg = strip * 16 + g * 4 + jj;
        Kb[(size_t)rg * 64 + cf * 16 + r] = (bf16)acc0[cf][jj];
      }
    int bb = (strip * 16) >> 11;
    int t0 = (strip * 16 + g * 4) & 2047;
    #pragma unroll
    for (int cf = 0; cf < 4; cf++) {
      bf16x4 v = (bf16x4){(bf16)acc1[cf][0], (bf16)acc1[cf][1],
                          (bf16)acc1[cf][2], (bf16)acc1[cf][3]};
      *(bf16x4*)&Vtb[((size_t)(bb * 64 + cf * 16 + r)) * 2048 + t0] = v;
    }
  }
}

// ---------------------------------------------------------------------------
// Kernel 2: causal flash attention. One change vs prior rounds: the barrier
// between the P->LDS write and the PV MFMA is REMOVED — Ps is per-wave
// private (same-wave ds_write->ds_read is in-order), and PV's other operand
// Vs was synced at tile start. Only the end-of-tile barrier (Ks/Vs WAR)
// remains: 2 barriers/tile -> 1 is structural.
// ---------------------------------------------------------------------------
__global__ __launch_bounds__(256) void attn_kernel(
    const bf16* __restrict__ Qb, const bf16* __restrict__ Kb,
    const bf16* __restrict__ Vtb, float* __restrict__ out)
{
  const int qt = (int)(gridDim.x - 1 - blockIdx.x);   // heavy blocks first
  const int b = blockIdx.y;
  const int tid = threadIdx.x;
  const int lane = tid & 63;
  const int w = tid >> 6;
  const int g = lane >> 4;
  const int r = lane & 15;

  __shared__ __align__(16) bf16 Ks[64][80];
  __shared__ __align__(16) bf16 Vs[64][80];
  __shared__ __align__(16) bf16 Ps[4][16][80];

  const int q0 = qt * 64 + w * 16;
  const bf16* qp = Qb + (size_t)(b * 2048 + q0 + r) * 64 + g * 8;
  const bf16x8 qf0 = *(const bf16x8*)qp;
  const bf16x8 qf1 = *(const bf16x8*)(qp + 32);

  f32x4 acc_o[4];
  #pragma unroll
  for (int hf = 0; hf < 4; hf++) acc_o[hf] = (f32x4){0.f, 0.f, 0.f, 0.f};
  float m_r[4] = {-1e30f, -1e30f, -1e30f, -1e30f};
  float l_r[4] = {0.f, 0.f, 0.f, 0.f};
  const float scale = 0.03125f;   // 1/sqrt(1024)

  const int sh = tid >> 2;
  const int sc = (tid & 3) * 16;

  for (int kv = 0; kv <= qt; kv++) {
    {
      const bf16* kp = Kb + (size_t)(b * 2048 + kv * 64 + sh) * 64 + sc;
      *(bf16x8*)&Ks[sh][sc]     = *(const bf16x8*)kp;
      *(bf16x8*)&Ks[sh][sc + 8] = *(const bf16x8*)(kp + 8);
      const bf16* vp = Vtb + (size_t)(b * 64 + sh) * 2048 + kv * 64 + sc;
      *(bf16x8*)&Vs[sh][sc]     = *(const bf16x8*)vp;
      *(bf16x8*)&Vs[sh][sc + 8] = *(const bf16x8*)(vp + 8);
    }
    __syncthreads();

    f32x4 s[4];
    #pragma unroll
    for (int cf = 0; cf < 4; cf++) {
      bf16x8 kf0 = *(const bf16x8*)&Ks[cf * 16 + r][g * 8];
      bf16x8 kf1 = *(const bf16x8*)&Ks[cf * 16 + r][32 + g * 8];
      f32x4 t = (f32x4){0.f, 0.f, 0.f, 0.f};
      t = MFMA_16x16x32(qf0, kf0, t);
      t = MFMA_16x16x32(qf1, kf1, t);
      s[cf] = t;
    }

    const bool diag = (kv == qt);
    float pm[4] = {-1e30f, -1e30f, -1e30f, -1e30f};
    #pragma unroll
    for (int cf = 0; cf < 4; cf++) {
      #pragma unroll
      for (int j = 0; j < 4; j++) {
        float v = s[cf][j] * scale;
        if (diag && (cf * 16 + r) > (w * 16 + g * 4 + j)) v = -1e30f;
        s[cf][j] = v;
        pm[j] = fmaxf(pm[j], v);
      }
    }
    #pragma unroll
    for (int j = 0; j < 4; j++) {
      #pragma unroll
      for (int msk = 1; msk < 16; msk <<= 1)
        pm[j] = fmaxf(pm[j], __shfl_xor(pm[j], msk, 64));
    }
    float corr[4];
    #pragma unroll
    for (int j = 0; j < 4; j++) {
      float mn = fmaxf(m_r[j], pm[j]);
      corr[j] = __expf(m_r[j] - mn);
      m_r[j] = mn;
    }
    float rs[4] = {0.f, 0.f, 0.f, 0.f};
    #pragma unroll
    for (int cf = 0; cf < 4; cf++) {
      #pragma unroll
      for (int j = 0; j < 4; j++) {
        float pv = __expf(s[cf][j] - m_r[j]);
        s[cf][j] = pv;
        rs[j] += pv;
      }
    }
    #pragma unroll
    for (int j = 0; j < 4; j++) {
      #pragma unroll
      for (int msk = 1; msk < 16; msk <<= 1)
        rs[j] += __shfl_xor(rs[j], msk, 64);
      l_r[j] = l_r[j] * corr[j] + rs[j];
    }
    #pragma unroll
    for (int hf = 0; hf < 4; hf++)
      #pragma unroll
      for (int j = 0; j < 4; j++)
        acc_o[hf][j] *= corr[j];

    // P (C-layout) -> per-wave LDS -> A-layout fragments.
    // Ps[w] is wave-private: in-order DS makes the round trip safe with
    // NO barrier here.
    #pragma unroll
    for (int cf = 0; cf < 4; cf++)
      #pragma unroll
      for (int j = 0; j < 4; j++)
        Ps[w][g * 4 + j][cf * 16 + r] = (bf16)s[cf][j];

    #pragma unroll
    for (int ss = 0; ss < 2; ss++) {
      bf16x8 pf = *(const bf16x8*)&Ps[w][r][ss * 32 + g * 8];
      #pragma unroll
      for (int hf = 0; hf < 4; hf++) {
        bf16x8 vf = *(const bf16x8*)&Vs[hf * 16 + r][ss * 32 + g * 8];
        acc_o[hf] = MFMA_16x16x32(pf, vf, acc_o[hf]);
      }
    }
    __syncthreads();   // Ks/Vs WAR before next tile's staging
  }

  float inv[4];
  #pragma unroll
  for (int j = 0; j < 4; j++) inv[j] = 1.0f / l_r[j];
  const size_t ob = (size_t)(b * 2048 + q0) * 64;
  #pragma unroll
  for (int hf = 0; hf < 4; hf++)
    #pragma unroll
    for (int j = 0; j < 4; j++)
      out[ob + (size_t)(g * 4 + j) * 64 + hf * 16 + r] = acc_o[hf][j] * inv[j];
}

// ---------------------------------------------------------------------------
extern "C" void kernel_launch(void* const* d_in, const int* in_sizes, int n_in,
                              void* d_out, int out_size, void* d_ws, size_t ws_size,
                              hipStream_t stream)
{
  const float* q  = (const float*)d_in[0];
  const float* k  = (const float*)d_in[1];
  const float* Wq = (const float*)d_in[2];
  const float* Wk = (const float*)d_in[3];
  const float* Wv = (const float*)d_in[4];
  float* out = (float*)d_out;

  char* ws = (char*)d_ws;
  bf16* Qb  = (bf16*)(ws);                      // [16*2048][64] bf16, 4MB
  bf16* Kb  = (bf16*)(ws + (4u << 20));         // [16*2048][64] bf16, 4MB
  bf16* Vtb = (bf16*)(ws + (8u << 20));         // [16][64][2048] bf16, 4MB
  bf16* Wt  = (bf16*)(ws + (12u << 20));        // [3][64][1024] bf16, 384KB

  hipLaunchKernelGGL(wtrans_kernel, dim3(768), dim3(256), 0, stream,
                     Wq, Wk, Wv, Wt);
  // dynamic LDS: (2 tiles * 17920 + 8 waves * 4480) elems * 2B = 143360 B
  hipLaunchKernelGGL(proj_kernel, dim3(512), dim3(512), 143360, stream,
                     q, k, Wt, Qb, Kb, Vtb);
  hipLaunchKernelGGL(attn_kernel, dim3(32, 16), dim3(256), 0, stream,
                     Qb, Kb, Vtb, out);
}

// Round 14
// 125.890 us; speedup vs baseline: 1.2082x; 1.2082x over previous
//
#include <hip/hip_runtime.h>
#include <hip/hip_bf16.h>

typedef __bf16 bf16;
typedef __bf16 bf16x4 __attribute__((ext_vector_type(4)));
typedef __bf16 bf16x8 __attribute__((ext_vector_type(8)));
typedef float f32x4 __attribute__((ext_vector_type(4)));

#define MFMA_16x16x32(A, B, C) __builtin_amdgcn_mfma_f32_16x16x32_bf16(A, B, C, 0, 0, 0)

static_assert(sizeof(bf16x8) == 16, "bf16x8 must be 16B");

// ---------------------------------------------------------------------------
// Kernel 0: cast + transpose weights: Wt[p][h][c] = W_p[c][h].
// ---------------------------------------------------------------------------
__global__ __launch_bounds__(256) void wtrans_kernel(
    const float* __restrict__ Wq, const float* __restrict__ Wk,
    const float* __restrict__ Wv, bf16* __restrict__ Wt)
{
  int idx = blockIdx.x * 256 + threadIdx.x;   // 3*64*1024
  int p = idx >> 16;
  int rem = idx & 65535;
  int h = rem >> 10;
  int c = rem & 1023;
  const float* W = (p == 0) ? Wq : (p == 1) ? Wk : Wv;
  Wt[idx] = (bf16)W[c * 64 + h];
}

// ---------------------------------------------------------------------------
// Kernel 1: projections — FINAL (best-measured: R12 build, 113 µs dispatch).
// 256 blocks x 1024 threads (16 waves), exactly 1 block/CU -> single
// dispatch round, no tail. ~148 KB dynamic LDS.
//  bid <128 : Q-family. Wq (128 KB) LDS-resident; wave w computes strip
//             bid*16+w (16 rows, full K) — EXACTLY 1 strip/wave.
//  bid>=128 : KV-family. k read ONCE; Wk+Wv staged per k-phase (4 phases
//             x 64 KB, 2 barriers each); acc for K AND V in registers.
// A loads are FULL-LINE (lane rl=lane>>2 reads 16B slot l4 of each 64B
// line -> 1 line-touch per line), redistributed to the MFMA fragment
// layout via a PER-WAVE bf16 LDS stage [16][40] (same-wave DS ops are
// in-order -> no barrier).
// 13 structural variants (DMA / reg-staged / at-use x barriered /
// counted-vmcnt / barrier-free x 8-21 waves/CU x fragment / full-line /
// address-sequential reads) all converge to 110-117 µs: this read
// pattern's delivered-traffic rate is pinned at ~2.3-2.4 TB/s on this
// part. This build is the floor configuration.
// ---------------------------------------------------------------------------
__global__ __launch_bounds__(1024, 4) void proj_kernel(
    const float* __restrict__ qin, const float* __restrict__ kin,
    const bf16* __restrict__ Wt,
    bf16* __restrict__ Qb, bf16* __restrict__ Kb, bf16* __restrict__ Vtb)
{
  extern __shared__ __align__(16) bf16 lds[];
  // layout: [0 .. 65535]   B-region (Q: [64][1024]; KV: 2 x [64][256] tiles)
  //         [65536 .. ]    16 waves x [16][40] bf16 A-stage
  const int tid = threadIdx.x;
  const int lane = tid & 63;
  const int w = tid >> 6;          // wave 0..15
  const int g = lane >> 4;
  const int r = lane & 15;
  const int rl = lane >> 2;        // full-line load: row 0..15
  const int l4 = lane & 3;         // full-line load: 16B slot in line

  bf16* const stageW = lds + 65536 + w * 640;   // [16][40] bf16 per wave

  const int bid = blockIdx.x;
  const bool isQ = (bid < 128);
  const int fbid = isQ ? bid : bid - 128;
  const int strip = fbid * 16 + w;              // 0..2047
  const float* A = isQ ? qin : kin;
  const float* ap = A + (size_t)strip * 16 * 1024;

  f32x4 acc0[4], acc1[4];
  #pragma unroll
  for (int cf = 0; cf < 4; cf++) {
    acc0[cf] = (f32x4){0.f, 0.f, 0.f, 0.f};
    acc1[cf] = (f32x4){0.f, 0.f, 0.f, 0.f};
  }

  // full-line A load for chunk c (32 floats/row), convert, redistribute,
  // return this lane's MFMA A-fragment (row r, k-slice g*8..g*8+7).
  auto afrag = [&](int c) -> bf16x8 {
    const float* rowp = ap + (size_t)rl * 1024 + c * 32 + l4 * 4;
    float4 a0 = *(const float4*)(rowp);        // line0: floats 0..15
    float4 a1 = *(const float4*)(rowp + 16);   // line1: floats 16..31
    bf16x4 w0 = (bf16x4){(bf16)a0.x, (bf16)a0.y, (bf16)a0.z, (bf16)a0.w};
    bf16x4 w1 = (bf16x4){(bf16)a1.x, (bf16)a1.y, (bf16)a1.z, (bf16)a1.w};
    *(bf16x4*)&stageW[rl * 40 + l4 * 4] = w0;        // cols l4*4..+3
    *(bf16x4*)&stageW[rl * 40 + 16 + l4 * 4] = w1;   // cols 16+l4*4..+3
    return *(const bf16x8*)&stageW[r * 40 + g * 8];  // in-order DS: safe
  };

  if (isQ) {
    // --- stage Wq [64][1024] once, chunk-swizzled ---
    #pragma unroll
    for (int i = 0; i < 8; ++i) {
      int cid = i * 1024 + tid;            // 16B chunk, 0..8191
      int row = cid >> 7, ch = cid & 127;
      int pch = ch ^ (row & 7);
      *(bf16x8*)&lds[row * 1024 + pch * 8] =
          *(const bf16x8*)(Wt + (size_t)row * 1024 + ch * 8);
    }
    __syncthreads();

    #pragma unroll 2
    for (int c = 0; c < 32; ++c) {
      bf16x8 af = afrag(c);
      #pragma unroll
      for (int cf = 0; cf < 4; cf++) {
        int rw = cf * 16 + r;
        int pch = (4 * c + g) ^ (rw & 7);
        bf16x8 bfr = *(const bf16x8*)&lds[rw * 1024 + pch * 8];
        acc0[cf] = MFMA_16x16x32(af, bfr, acc0[cf]);
      }
    }

    #pragma unroll
    for (int cf = 0; cf < 4; cf++)
      #pragma unroll
      for (int jj = 0; jj < 4; jj++) {
        int rg = strip * 16 + g * 4 + jj;
        Qb[(size_t)rg * 64 + cf * 16 + r] = (bf16)acc0[cf][jj];
      }
  } else {
    // --- KV: 4 k-phases; per phase stage Wk,Wv tiles [64][256] ---
    for (int p = 0; p < 4; ++p) {
      __syncthreads();   // previous phase's reads done (WAR)
      #pragma unroll
      for (int i = 0; i < 2; ++i) {
        int cid = i * 1024 + tid;          // 0..2047 chunks per tile
        int row = cid >> 5, ch = cid & 31;
        int pch = ch ^ (row & 7);
        *(bf16x8*)&lds[row * 256 + pch * 8] =
            *(const bf16x8*)(Wt + 65536 + (size_t)row * 1024 + p * 256 + ch * 8);
        *(bf16x8*)&lds[16384 + row * 256 + pch * 8] =
            *(const bf16x8*)(Wt + 2 * 65536 + (size_t)row * 1024 + p * 256 + ch * 8);
      }
      __syncthreads();

      #pragma unroll 2
      for (int cl = 0; cl < 8; ++cl) {
        bf16x8 af = afrag(p * 8 + cl);
        #pragma unroll
        for (int cf = 0; cf < 4; cf++) {
          int rw = cf * 16 + r;
          int pch = (4 * cl + g) ^ (rw & 7);
          bf16x8 b0 = *(const bf16x8*)&lds[rw * 256 + pch * 8];
          acc0[cf] = MFMA_16x16x32(af, b0, acc0[cf]);
          bf16x8 b1 = *(const bf16x8*)&lds[16384 + rw * 256 + pch * 8];
          acc1[cf] = MFMA_16x16x32(af, b1, acc1[cf]);
        }
      }
    }

    // K row-major; V transposed Vt[b][h][t] (4 consecutive-t packed -> 8B)
    #pragma unroll
    for (int cf = 0; cf < 4; cf++)
      #pragma unroll
      for (int jj = 0; jj < 4; jj++) {
        int rg = strip * 16 + g * 4 + jj;
        Kb[(size_t)rg * 64 + cf * 16 + r] = (bf16)acc0[cf][jj];
      }
    int bb = (strip * 16) >> 11;
    int t0 = (strip * 16 + g * 4) & 2047;
    #pragma unroll
    for (int cf = 0; cf < 4; cf++) {
      bf16x4 v = (bf16x4){(bf16)acc1[cf][0], (bf16)acc1[cf][1],
                          (bf16)acc1[cf][2], (bf16)acc1[cf][3]};
      *(bf16x4*)&Vtb[((size_t)(bb * 64 + cf * 16 + r)) * 2048 + t0] = v;
    }
  }
}

// ---------------------------------------------------------------------------
// Kernel 2: causal flash attention (best-measured build).
// ---------------------------------------------------------------------------
__global__ __launch_bounds__(256) void attn_kernel(
    const bf16* __restrict__ Qb, const bf16* __restrict__ Kb,
    const bf16* __restrict__ Vtb, float* __restrict__ out)
{
  const int qt = (int)(gridDim.x - 1 - blockIdx.x);   // heavy blocks first
  const int b = blockIdx.y;
  const int tid = threadIdx.x;
  const int lane = tid & 63;
  const int w = tid >> 6;
  const int g = lane >> 4;
  const int r = lane & 15;

  __shared__ __align__(16) bf16 Ks[64][80];
  __shared__ __align__(16) bf16 Vs[64][80];
  __shared__ __align__(16) bf16 Ps[4][16][80];

  const int q0 = qt * 64 + w * 16;
  const bf16* qp = Qb + (size_t)(b * 2048 + q0 + r) * 64 + g * 8;
  const bf16x8 qf0 = *(const bf16x8*)qp;
  const bf16x8 qf1 = *(const bf16x8*)(qp + 32);

  f32x4 acc_o[4];
  #pragma unroll
  for (int hf = 0; hf < 4; hf++) acc_o[hf] = (f32x4){0.f, 0.f, 0.f, 0.f};
  float m_r[4] = {-1e30f, -1e30f, -1e30f, -1e30f};
  float l_r[4] = {0.f, 0.f, 0.f, 0.f};
  const float scale = 0.03125f;   // 1/sqrt(1024)

  const int sh = tid >> 2;
  const int sc = (tid & 3) * 16;

  for (int kv = 0; kv <= qt; kv++) {
    {
      const bf16* kp = Kb + (size_t)(b * 2048 + kv * 64 + sh) * 64 + sc;
      *(bf16x8*)&Ks[sh][sc]     = *(const bf16x8*)kp;
      *(bf16x8*)&Ks[sh][sc + 8] = *(const bf16x8*)(kp + 8);
      const bf16* vp = Vtb + (size_t)(b * 64 + sh) * 2048 + kv * 64 + sc;
      *(bf16x8*)&Vs[sh][sc]     = *(const bf16x8*)vp;
      *(bf16x8*)&Vs[sh][sc + 8] = *(const bf16x8*)(vp + 8);
    }
    __syncthreads();

    f32x4 s[4];
    #pragma unroll
    for (int cf = 0; cf < 4; cf++) {
      bf16x8 kf0 = *(const bf16x8*)&Ks[cf * 16 + r][g * 8];
      bf16x8 kf1 = *(const bf16x8*)&Ks[cf * 16 + r][32 + g * 8];
      f32x4 t = (f32x4){0.f, 0.f, 0.f, 0.f};
      t = MFMA_16x16x32(qf0, kf0, t);
      t = MFMA_16x16x32(qf1, kf1, t);
      s[cf] = t;
    }

    const bool diag = (kv == qt);
    float pm[4] = {-1e30f, -1e30f, -1e30f, -1e30f};
    #pragma unroll
    for (int cf = 0; cf < 4; cf++) {
      #pragma unroll
      for (int j = 0; j < 4; j++) {
        float v = s[cf][j] * scale;
        if (diag && (cf * 16 + r) > (w * 16 + g * 4 + j)) v = -1e30f;
        s[cf][j] = v;
        pm[j] = fmaxf(pm[j], v);
      }
    }
    #pragma unroll
    for (int j = 0; j < 4; j++) {
      #pragma unroll
      for (int msk = 1; msk < 16; msk <<= 1)
        pm[j] = fmaxf(pm[j], __shfl_xor(pm[j], msk, 64));
    }
    float corr[4];
    #pragma unroll
    for (int j = 0; j < 4; j++) {
      float mn = fmaxf(m_r[j], pm[j]);
      corr[j] = __expf(m_r[j] - mn);
      m_r[j] = mn;
    }
    float rs[4] = {0.f, 0.f, 0.f, 0.f};
    #pragma unroll
    for (int cf = 0; cf < 4; cf++) {
      #pragma unroll
      for (int j = 0; j < 4; j++) {
        float pv = __expf(s[cf][j] - m_r[j]);
        s[cf][j] = pv;
        rs[j] += pv;
      }
    }
    #pragma unroll
    for (int j = 0; j < 4; j++) {
      #pragma unroll
      for (int msk = 1; msk < 16; msk <<= 1)
        rs[j] += __shfl_xor(rs[j], msk, 64);
      l_r[j] = l_r[j] * corr[j] + rs[j];
    }
    #pragma unroll
    for (int hf = 0; hf < 4; hf++)
      #pragma unroll
      for (int j = 0; j < 4; j++)
        acc_o[hf][j] *= corr[j];

    #pragma unroll
    for (int cf = 0; cf < 4; cf++)
      #pragma unroll
      for (int j = 0; j < 4; j++)
        Ps[w][g * 4 + j][cf * 16 + r] = (bf16)s[cf][j];

    __syncthreads();

    #pragma unroll
    for (int ss = 0; ss < 2; ss++) {
      bf16x8 pf = *(const bf16x8*)&Ps[w][r][ss * 32 + g * 8];
      #pragma unroll
      for (int hf = 0; hf < 4; hf++) {
        bf16x8 vf = *(const bf16x8*)&Vs[hf * 16 + r][ss * 32 + g * 8];
        acc_o[hf] = MFMA_16x16x32(pf, vf, acc_o[hf]);
      }
    }
    __syncthreads();
  }

  float inv[4];
  #pragma unroll
  for (int j = 0; j < 4; j++) inv[j] = 1.0f / l_r[j];
  const size_t ob = (size_t)(b * 2048 + q0) * 64;
  #pragma unroll
  for (int hf = 0; hf < 4; hf++)
    #pragma unroll
    for (int j = 0; j < 4; j++)
      out[ob + (size_t)(g * 4 + j) * 64 + hf * 16 + r] = acc_o[hf][j] * inv[j];
}

// ---------------------------------------------------------------------------
extern "C" void kernel_launch(void* const* d_in, const int* in_sizes, int n_in,
                              void* d_out, int out_size, void* d_ws, size_t ws_size,
                              hipStream_t stream)
{
  const float* q  = (const float*)d_in[0];
  const float* k  = (const float*)d_in[1];
  const float* Wq = (const float*)d_in[2];
  const float* Wk = (const float*)d_in[3];
  const float* Wv = (const float*)d_in[4];
  float* out = (float*)d_out;

  char* ws = (char*)d_ws;
  bf16* Qb  = (bf16*)(ws);                      // [16*2048][64] bf16, 4MB
  bf16* Kb  = (bf16*)(ws + (4u << 20));         // [16*2048][64] bf16, 4MB
  bf16* Vtb = (bf16*)(ws + (8u << 20));         // [16][64][2048] bf16, 4MB
  bf16* Wt  = (bf16*)(ws + (12u << 20));        // [3][64][1024] bf16, 384KB

  hipLaunchKernelGGL(wtrans_kernel, dim3(768), dim3(256), 0, stream,
                     Wq, Wk, Wv, Wt);
  // dynamic LDS: 131072 (B region) + 16 waves * 640 bf16 * 2B = 151552 B
  hipLaunchKernelGGL(proj_kernel, dim3(256), dim3(1024), 151552, stream,
                     q, k, Wt, Qb, Kb, Vtb);
  hipLaunchKernelGGL(attn_kernel, dim3(32, 16), dim3(256), 0, stream,
                     Qb, Kb, Vtb, out);
}